// Round 18
// baseline (6293.362 us; speedup 1.0000x reference)
//
#include <hip/hip_runtime.h>
#include <hip/hip_bf16.h>

#define T_STEPS 512
#define BATCH   64
#define HID     1024
#define NBLK    256         // 128 scan WGs + 128 xproj workers
#define NSLOT   32          // rotating exchange slots
#define SLOT_SH (4 * 16 * 1024)   // shorts per slot

typedef __attribute__((ext_vector_type(8))) short short8;
typedef __attribute__((ext_vector_type(4))) float f32x4;
typedef __attribute__((ext_vector_type(4))) int  i32x4;

static __device__ __forceinline__ float b2f(unsigned short u){
  union { unsigned u; float f; } c; c.u = ((unsigned)u) << 16; return c.f;
}
static __device__ __forceinline__ unsigned short f2b(float f){
  union { float f; unsigned u; } c; c.f = f;
  unsigned r = c.u + 0x7fffu + ((c.u >> 16) & 1u);
  return (unsigned short)(r >> 16);
}
static __device__ __forceinline__ float sigm(float x){ return 1.0f / (1.0f + __expf(-x)); }
static __device__ __forceinline__ float tanh_fast(float x){ return 2.0f / (1.0f + __expf(-2.0f * x)) - 1.0f; }

#define MFMA __builtin_amdgcn_mfma_f32_16x16x32_bf16

// ---------------- init: zero flags + G2-ready counters ----------------
__global__ void gru_init_k(int* __restrict__ flags, int* __restrict__ gready){
  int i = blockIdx.x * blockDim.x + threadIdx.x;
  if (i < 4 * 32 * 32)
    __hip_atomic_store(flags + i, 0, __ATOMIC_RELAXED, __HIP_MEMORY_SCOPE_AGENT);
  if (i < T_STEPS * 32)
    __hip_atomic_store(gready + i, 0, __ATOMIC_RELAXED, __HIP_MEMORY_SCOPE_AGENT);
}

// ---------------- transpose + cast weights: Wt[g][n][k] = W_g[k][n] ----------------
__global__ void gru_prepw_k(const float* __restrict__ w0, const float* __restrict__ w1,
                            const float* __restrict__ w2, const float* __restrict__ w3,
                            const float* __restrict__ w4, const float* __restrict__ w5,
                            unsigned short* __restrict__ wt){
  __shared__ float tile[32][33];
  const float* src;
  switch (blockIdx.z){
    case 0: src = w0; break; case 1: src = w1; break; case 2: src = w2; break;
    case 3: src = w3; break; case 4: src = w4; break; default: src = w5; break;
  }
  int tx = threadIdx.x, ty = threadIdx.y;
  int x0 = blockIdx.x * 32, y0 = blockIdx.y * 32;
  #pragma unroll
  for (int i = 0; i < 32; i += 8)
    tile[ty + i][tx] = src[(size_t)(y0 + ty + i) * HID + x0 + tx];
  __syncthreads();
  unsigned short* dst = wt + (size_t)blockIdx.z * HID * HID;
  #pragma unroll
  for (int i = 0; i < 32; i += 8)
    dst[(size_t)(x0 + ty + i) * HID + y0 + tx] = f2b(tile[tx][ty + i]);
}

// ---- poll: 32 lanes, one flag each (flags 128B apart), light backoff ----
static __device__ __forceinline__ void waitflags32(const int* fgrp, int target){
  const int lane = threadIdx.x & 63;
  const int* p = fgrp + (lane & 31) * 32;
  const bool mine = lane < 32;
  for (;;){
    int v = mine ? __hip_atomic_load(p, __ATOMIC_RELAXED, __HIP_MEMORY_SCOPE_AGENT)
                 : 0x7fffffff;
    if (__all(v >= target)) return;
    __builtin_amdgcn_s_sleep(1);
  }
}

// ---- write-through stores to MALL (sc0 sc1) ----
static __device__ __forceinline__ void pub16(unsigned short* dst, const unsigned short* lds_src){
  i32x4 v = *(const i32x4*)lds_src;
  asm volatile("global_store_dwordx4 %0, %1, off sc0 sc1" :: "v"(dst), "v"(v) : "memory");
}
static __device__ __forceinline__ void pub8(unsigned short* dst, unsigned long long v){
  asm volatile("global_store_dwordx2 %0, %1, off sc0 sc1" :: "v"(dst), "v"(v) : "memory");
}

// ---------------- merged kernel: 128 scan WGs + 128 xproj workers ----------------
__global__ __launch_bounds__(512, 1) void gru_main_k(
    const float* __restrict__ inp,            // [32768][1024] fp32
    const unsigned short* __restrict__ wt,    // [6][1024][1024] bf16 [n][k]
    const float* __restrict__ bz, const float* __restrict__ br, const float* __restrict__ bh,
    unsigned short* __restrict__ G2,          // [512][3][2][1024][32] bf16
    float* __restrict__ out,                  // [T][64][1024] fp32 + [64][1024] H_final
    unsigned short* __restrict__ hb,          // [NSLOT][4][16][1024] bf16 H slots
    unsigned short* __restrict__ rh,          // [NSLOT][4][16][1024] bf16 R*H slots
    int* __restrict__ flags,                  // [4][32][32] (128B-strided)
    int* __restrict__ gready)                 // [512][32] (128B-strided)
{
  __shared__ __align__(16) char smem[98304];  // 96 KiB -> exactly 1 WG/CU
  const int bid = blockIdx.x;
  const int tid = threadIdx.x;

  if (bid >= 128){
    // ================= xproj worker: 24 tiles in ascending-t order =================
    const int d = bid - 128;
    const int wv = tid >> 6, lane = tid & 63;
    const int l16 = lane & 15, kq = lane >> 4;
    char* sb = (char*)smem;                       // 64 KiB A-tile
    const int asw = (l16 & 7) << 4;

    for (int i = 0; i < 24; ++i){
      const int tau = i * 128 + d;
      const int tt = tau / 6, rem = tau % 6, g = rem >> 1, rhh = rem & 1;
      const float* bias_p = (g == 0) ? bz : (g == 1) ? br : bh;

      const float* abase = inp + ((size_t)tt * 64 + rhh * 32) * HID;
      #pragma unroll
      for (int p = 0; p < 16; ++p){
        int e = (p * 512 + tid) * 4;
        float4 v = *(const float4*)(abase + e);
        ushort4 o;
        o.x = f2b(v.x); o.y = f2b(v.y); o.z = f2b(v.z); o.w = f2b(v.w);
        int b = e * 2;
        *(ushort4*)(sb + (b ^ (((b >> 11) & 7) << 4))) = o;
      }
      __syncthreads();

      const int n0 = wv * 128;
      const unsigned short* wslab = wt + (size_t)(2 * g) * HID * HID;
      const unsigned short* wcol[8];
      float bias[8];
      #pragma unroll
      for (int c = 0; c < 8; ++c){
        int n = n0 + c * 16 + l16;
        wcol[c] = wslab + (size_t)n * HID + kq * 8;
        bias[c] = bias_p[n];
      }
      f32x4 acc[2][8];
      #pragma unroll
      for (int r = 0; r < 2; ++r)
        #pragma unroll
        for (int c = 0; c < 8; ++c) acc[r][c] = (f32x4){0.f,0.f,0.f,0.f};

      for (int kk = 0; kk < HID; kk += 32){
        short8 a0 = *(const short8*)(sb + ((l16 * 2048 + kk * 2 + kq * 16) ^ asw));
        short8 a1 = *(const short8*)(sb + (((16 + l16) * 2048 + kk * 2 + kq * 16) ^ asw));
        #pragma unroll
        for (int c = 0; c < 8; ++c){
          short8 bf = *(const short8*)(wcol[c] + kk);
          acc[0][c] = MFMA(a0, bf, acc[0][c], 0, 0, 0);
          acc[1][c] = MFMA(a1, bf, acc[1][c], 0, 0, 0);
        }
      }

      unsigned short* gout = G2 + (((size_t)tt * 3 + g) * 2 + rhh) * 32768;
      #pragma unroll
      for (int c = 0; c < 8; ++c){
        int n = n0 + c * 16 + l16;
        #pragma unroll
        for (int r = 0; r < 2; ++r){
          unsigned lo = (unsigned)f2b(acc[r][c][0] + bias[c]) | ((unsigned)f2b(acc[r][c][1] + bias[c]) << 16);
          unsigned hi = (unsigned)f2b(acc[r][c][2] + bias[c]) | ((unsigned)f2b(acc[r][c][3] + bias[c]) << 16);
          pub8(&gout[(size_t)n * 32 + r * 16 + kq * 4],
               (unsigned long long)lo | ((unsigned long long)hi << 32));
        }
      }
      asm volatile("s_waitcnt vmcnt(0)" ::: "memory");
      __syncthreads();
      if (tid == 0)
        __hip_atomic_fetch_add(gready + tt * 32, 1, __ATOMIC_RELAXED, __HIP_MEMORY_SCOPE_AGENT);
    }
    return;
  }

  // ================= scan WG: per-wave polls, direct MALL A-reads, 2 barriers ==========
  float*          zlds    = (float*)smem;                      // 16*33 fp32
  float*          hlds    = (float*)(smem + 2112);             // 16*33 fp32
  unsigned short* ostageR = (unsigned short*)(smem + 4224);    // 1 KiB
  unsigned short* ostageH = (unsigned short*)(smem + 5248);    // 1 KiB

  const int rg  = bid & 3;
  const int cs  = bid >> 2;
  const int w    = tid >> 6;
  const int lane = tid & 63;
  const int l16  = lane & 15;
  const int kq   = lane >> 4;

  const int myct = w & 1;                      // col-tile for compute waves
  const int col  = cs * 32 + myct * 16 + l16;
  const int gA   = (w >> 1) & 1;               // w0-1: Z(0), w2-3: R(1)
  const int erow0 = kq * 4;
  const int ecol  = myct * 16 + l16;

  short8 wreg[32];
  if (w < 6){
    const int slot = (w < 2) ? 1 : (w < 4) ? 3 : 5;   // Whz / Whr / Whh
    const unsigned short* p = wt + (size_t)slot * HID * HID + (size_t)col * HID + kq * 8;
    #pragma unroll
    for (int i = 0; i < 32; ++i) wreg[i] = *(const short8*)(p + i * 32);
  }

  int* fgrp   = flags + rg * 32 * 32;
  int* myflag = fgrp + cs * 32;

  for (int i = tid; i < 16 * 33; i += 512) hlds[i] = 0.f;
  __syncthreads();

  const int afo = l16 * 1024 + kq * 8;           // A-frag base (shorts) in [16][1024] tile
  const int prow = lane >> 2, pc8 = (lane & 3) * 8;   // publish mapping (wave 7)

  const size_t g2rh = (size_t)(rg >> 1) * 32768;
  const int    g2r  = (rg & 1) * 16 + erow0;

  for (int t = 0; t < T_STEPS; ++t){
    unsigned short* hb_w = hb + (size_t)(t & (NSLOT - 1)) * SLOT_SH + rg * 16384;
    unsigned short* rh_w = rh + (size_t)(t & (NSLOT - 1)) * SLOT_SH + rg * 16384;
    const unsigned short* hb_r = hb + (size_t)((t - 1) & (NSLOT - 1)) * SLOT_SH + rg * 16384;

    // gate availability of this step's G2 tile + load gx (agent, off critical path)
    unsigned long long gx = 0;
    if (w < 6){
      const int* gp = gready + t * 32;
      int v = (lane == 0) ? __hip_atomic_load(gp, __ATOMIC_RELAXED, __HIP_MEMORY_SCOPE_AGENT) : 6;
      while (!__all(v >= 6)){
        __builtin_amdgcn_s_sleep(2);
        v = (lane == 0) ? __hip_atomic_load(gp, __ATOMIC_RELAXED, __HIP_MEMORY_SCOPE_AGENT) : 6;
      }
      const int gate = (w < 4) ? gA : 2;
      gx = __hip_atomic_load((const unsigned long long*)
             (G2 + ((size_t)t * 3 + gate) * 65536 + g2rh + (size_t)col * 32 + g2r),
             __ATOMIC_RELAXED, __HIP_MEMORY_SCOPE_AGENT);
    }

    // ---- phase A: Z (w0-1) / R (w2-3); per-wave poll + direct cached A-reads ----
    if (w < 4){
      f32x4 a0 = {0.f,0.f,0.f,0.f}, a1 = {0.f,0.f,0.f,0.f};
      if (t){
        waitflags32(fgrp, 2 * t);                  // H_{t-1} published by row-group
        const unsigned short* ap = hb_r + afo;
        #pragma unroll
        for (int i = 0; i < 32; i += 2){
          short8 f0 = *(const short8*)(ap + i * 32);
          short8 f1 = *(const short8*)(ap + i * 32 + 32);
          a0 = MFMA(f0, wreg[i],     a0, 0, 0, 0);
          a1 = MFMA(f1, wreg[i + 1], a1, 0, 0, 0);
        }
      }
      #pragma unroll
      for (int j = 0; j < 4; ++j){
        float g = sigm(a0[j] + a1[j] + b2f((unsigned short)(gx >> (16 * j))));
        if (w < 2) zlds[(erow0 + j) * 33 + ecol] = g;                       // Z
        else       ostageR[(erow0 + j) * 32 + ecol] =
                     f2b(g * hlds[(erow0 + j) * 33 + ecol]);                // R*H
      }
    }
    __syncthreads();                               // B1: zlds / ostageR visible

    if (t && w == 7){
      pub16(rh_w + prow * 1024 + cs * 32 + pc8, &ostageR[lane * 8]);
      if (lane == 0){
        asm volatile("s_waitcnt vmcnt(0)" ::: "memory");
        __hip_atomic_store(myflag, 2 * t + 1, __ATOMIC_RELAXED, __HIP_MEMORY_SCOPE_AGENT);
      }
    }

    // ---- phase B: H_tilde + combine (w4-5); per-wave poll + direct reads ----
    float hn[4];
    if (w == 4 || w == 5){
      f32x4 a0 = {0.f,0.f,0.f,0.f}, a1 = {0.f,0.f,0.f,0.f};
      if (t){
        waitflags32(fgrp, 2 * t + 1);              // R*H published by row-group
        const unsigned short* ap = rh_w + afo;
        #pragma unroll
        for (int i = 0; i < 32; i += 2){
          short8 f0 = *(const short8*)(ap + i * 32);
          short8 f1 = *(const short8*)(ap + i * 32 + 32);
          a0 = MFMA(f0, wreg[i],     a0, 0, 0, 0);
          a1 = MFMA(f1, wreg[i + 1], a1, 0, 0, 0);
        }
      }
      #pragma unroll
      for (int j = 0; j < 4; ++j){
        int i33 = (erow0 + j) * 33 + ecol;
        float ht = tanh_fast(a0[j] + a1[j] + b2f((unsigned short)(gx >> (16 * j))));
        float z  = zlds[i33], hp = hlds[i33];
        hn[j] = z * hp + (1.0f - z) * ht;
        hlds[i33] = hn[j];
        ostageH[(erow0 + j) * 32 + ecol] = f2b(hn[j]);
      }
    }
    __syncthreads();                               // B2: hlds / ostageH visible

    if (t < T_STEPS - 1 && w == 7){
      pub16(hb_w + prow * 1024 + cs * 32 + pc8, &ostageH[lane * 8]);
      if (lane == 0){
        asm volatile("s_waitcnt vmcnt(0)" ::: "memory");
        __hip_atomic_store(myflag, 2 * t + 2, __ATOMIC_RELAXED, __HIP_MEMORY_SCOPE_AGENT);
      }
    }
    // out stores: off the critical path
    if (w == 4 || w == 5){
      #pragma unroll
      for (int j = 0; j < 4; ++j){
        __builtin_nontemporal_store(hn[j],
            &out[((size_t)t * BATCH + rg * 16 + erow0 + j) * HID + col]);
        if (t == T_STEPS - 1)
          __builtin_nontemporal_store(hn[j],
              &out[(size_t)T_STEPS * BATCH * HID + (size_t)(rg * 16 + erow0 + j) * HID + col]);
      }
    }
  }
}

extern "C" void kernel_launch(void* const* d_in, const int* in_sizes, int n_in,
                              void* d_out, int out_size, void* d_ws, size_t ws_size,
                              hipStream_t stream){
  const float* inputs = (const float*)d_in[0];
  const float* W_xz = (const float*)d_in[1];
  const float* W_hz = (const float*)d_in[2];
  const float* b_z  = (const float*)d_in[3];
  const float* W_xr = (const float*)d_in[4];
  const float* W_hr = (const float*)d_in[5];
  const float* b_r  = (const float*)d_in[6];
  const float* W_xh = (const float*)d_in[7];
  const float* W_hh = (const float*)d_in[8];
  const float* b_h  = (const float*)d_in[9];
  float* out = (float*)d_out;

  char* ws = (char*)d_ws;
  int*            flags  = (int*)ws;                                 // 16 KiB (128B-strided)
  int*            gready = (int*)(ws + 16384);                       // 64 KiB (128B-strided)
  unsigned short* hb     = (unsigned short*)(ws + 81920);            // 4 MiB (32 slots)
  unsigned short* rh     = (unsigned short*)(ws + 81920 + 4194304);  // 4 MiB
  unsigned short* wt     = (unsigned short*)(ws + 81920 + 8388608);  // 12 MiB
  unsigned short* G2     = (unsigned short*)(ws + 81920 + 8388608 + 12582912); // 192 MiB
  // total ws needed: ~213 MB

  gru_init_k<<<64, 256, 0, stream>>>(flags, gready);
  gru_prepw_k<<<dim3(32, 32, 6), dim3(32, 8), 0, stream>>>(W_xz, W_hz, W_xr, W_hr, W_xh, W_hh, wt);
  gru_main_k<<<NBLK, 512, 0, stream>>>(inputs, wt, b_z, b_r, b_h, G2, out, hb, rh, flags, gready);
}

// Round 19
// 3015.882 us; speedup vs baseline: 2.0867x; 2.0867x over previous
//
#include <hip/hip_runtime.h>
#include <hip/hip_bf16.h>

#define T_STEPS 512
#define BATCH   64
#define HID     1024
#define NBLK    256         // 128 scan WGs + 128 xproj workers
#define NSLOT   32          // rotating exchange slots
#define SLOT_SH (4 * 16 * 1024)   // shorts per slot

typedef __attribute__((ext_vector_type(8))) short short8;
typedef __attribute__((ext_vector_type(4))) float f32x4;
typedef __attribute__((ext_vector_type(4))) int  i32x4;

static __device__ __forceinline__ float b2f(unsigned short u){
  union { unsigned u; float f; } c; c.u = ((unsigned)u) << 16; return c.f;
}
static __device__ __forceinline__ unsigned short f2b(float f){
  union { float f; unsigned u; } c; c.f = f;
  unsigned r = c.u + 0x7fffu + ((c.u >> 16) & 1u);
  return (unsigned short)(r >> 16);
}
static __device__ __forceinline__ float sigm(float x){ return 1.0f / (1.0f + __expf(-x)); }
static __device__ __forceinline__ float tanh_fast(float x){ return 2.0f / (1.0f + __expf(-2.0f * x)) - 1.0f; }

#define MFMA __builtin_amdgcn_mfma_f32_16x16x32_bf16

// ---------------- init: zero flags + G2-ready counters ----------------
__global__ void gru_init_k(int* __restrict__ flags, int* __restrict__ gready){
  int i = blockIdx.x * blockDim.x + threadIdx.x;
  if (i < 4 * 32 * 32)
    __hip_atomic_store(flags + i, 0, __ATOMIC_RELAXED, __HIP_MEMORY_SCOPE_AGENT);
  if (i < T_STEPS * 32)
    __hip_atomic_store(gready + i, 0, __ATOMIC_RELAXED, __HIP_MEMORY_SCOPE_AGENT);
}

// ---------------- transpose + cast weights: Wt[g][n][k] = W_g[k][n] ----------------
__global__ void gru_prepw_k(const float* __restrict__ w0, const float* __restrict__ w1,
                            const float* __restrict__ w2, const float* __restrict__ w3,
                            const float* __restrict__ w4, const float* __restrict__ w5,
                            unsigned short* __restrict__ wt){
  __shared__ float tile[32][33];
  const float* src;
  switch (blockIdx.z){
    case 0: src = w0; break; case 1: src = w1; break; case 2: src = w2; break;
    case 3: src = w3; break; case 4: src = w4; break; default: src = w5; break;
  }
  int tx = threadIdx.x, ty = threadIdx.y;
  int x0 = blockIdx.x * 32, y0 = blockIdx.y * 32;
  #pragma unroll
  for (int i = 0; i < 32; i += 8)
    tile[ty + i][tx] = src[(size_t)(y0 + ty + i) * HID + x0 + tx];
  __syncthreads();
  unsigned short* dst = wt + (size_t)blockIdx.z * HID * HID;
  #pragma unroll
  for (int i = 0; i < 32; i += 8)
    dst[(size_t)(x0 + ty + i) * HID + y0 + tx] = f2b(tile[tx][ty + i]);
}

// ---- poll: 32 lanes, one flag each (flags 128B apart), light backoff ----
static __device__ __forceinline__ void waitflags32(const int* fgrp, int target){
  const int lane = threadIdx.x & 63;
  const int* p = fgrp + (lane & 31) * 32;
  const bool mine = lane < 32;
  for (;;){
    int v = mine ? __hip_atomic_load(p, __ATOMIC_RELAXED, __HIP_MEMORY_SCOPE_AGENT)
                 : 0x7fffffff;
    if (__all(v >= target)) return;
    __builtin_amdgcn_s_sleep(1);
  }
}

// ---- stage 16x1024 bf16 tile (32KB): lane-contiguous 16B chunks ----
static __device__ __forceinline__ void stage_in(const unsigned short* __restrict__ src,
                                                unsigned short* __restrict__ stg, int tid){
  char* sb = (char*)stg;
  const char* sc = (const char*)src;
  #pragma unroll
  for (int c = 0; c < 4; ++c){
    const int b = tid * 16 + c * 8192;
    short8 v = __builtin_nontemporal_load((const short8*)(sc + b));
    *(short8*)(sb + (b ^ (((b >> 11) & 7) << 4))) = v;
  }
}

// ---- write-through stores to MALL (sc0 sc1) ----
static __device__ __forceinline__ void pub16(unsigned short* dst, const unsigned short* lds_src){
  i32x4 v = *(const i32x4*)lds_src;
  asm volatile("global_store_dwordx4 %0, %1, off sc0 sc1" :: "v"(dst), "v"(v) : "memory");
}
static __device__ __forceinline__ void pub8(unsigned short* dst, unsigned long long v){
  asm volatile("global_store_dwordx2 %0, %1, off sc0 sc1" :: "v"(dst), "v"(v) : "memory");
}

// ---------------- merged kernel: 128 scan WGs + 128 xproj workers ----------------
__global__ __launch_bounds__(512, 1) void gru_main_k(
    const float* __restrict__ inp,            // [32768][1024] fp32
    const unsigned short* __restrict__ wt,    // [6][1024][1024] bf16 [n][k]
    const float* __restrict__ bz, const float* __restrict__ br, const float* __restrict__ bh,
    unsigned short* __restrict__ G2,          // [512][3][2][1024][32] bf16
    float* __restrict__ out,                  // [T][64][1024] fp32 + [64][1024] H_final
    unsigned short* __restrict__ hb,          // [NSLOT][4][16][1024] bf16 H slots
    unsigned short* __restrict__ rh,          // [NSLOT][4][16][1024] bf16 R*H slots
    int* __restrict__ flags,                  // [4][32][32] (128B-strided)
    int* __restrict__ gready)                 // [512][32] (128B-strided)
{
  __shared__ __align__(16) char smem[98304];  // 96 KiB -> exactly 1 WG/CU
  const int bid = blockIdx.x;
  const int tid = threadIdx.x;

  if (bid >= 128){
    // ================= xproj worker: 24 tiles in ascending-t order =================
    const int d = bid - 128;
    const int wv = tid >> 6, lane = tid & 63;
    const int l16 = lane & 15, kq = lane >> 4;
    char* sb = (char*)smem;                       // 64 KiB A-tile
    const int asw = (l16 & 7) << 4;

    for (int i = 0; i < 24; ++i){
      const int tau = i * 128 + d;
      const int tt = tau / 6, rem = tau % 6, g = rem >> 1, rhh = rem & 1;
      const float* bias_p = (g == 0) ? bz : (g == 1) ? br : bh;

      // stage + convert A: 32 rows x 1024 k, fp32 -> bf16, swizzled
      const float* abase = inp + ((size_t)tt * 64 + rhh * 32) * HID;
      #pragma unroll
      for (int p = 0; p < 16; ++p){
        int e = (p * 512 + tid) * 4;
        float4 v = *(const float4*)(abase + e);
        ushort4 o;
        o.x = f2b(v.x); o.y = f2b(v.y); o.z = f2b(v.z); o.w = f2b(v.w);
        int b = e * 2;
        *(ushort4*)(sb + (b ^ (((b >> 11) & 7) << 4))) = o;
      }
      __syncthreads();

      const int n0 = wv * 128;
      const unsigned short* wslab = wt + (size_t)(2 * g) * HID * HID;
      const unsigned short* wcol[8];
      float bias[8];
      #pragma unroll
      for (int c = 0; c < 8; ++c){
        int n = n0 + c * 16 + l16;
        wcol[c] = wslab + (size_t)n * HID + kq * 8;
        bias[c] = bias_p[n];
      }
      f32x4 acc[2][8];
      #pragma unroll
      for (int r = 0; r < 2; ++r)
        #pragma unroll
        for (int c = 0; c < 8; ++c) acc[r][c] = (f32x4){0.f,0.f,0.f,0.f};

      for (int kk = 0; kk < HID; kk += 32){
        short8 a0 = *(const short8*)(sb + ((l16 * 2048 + kk * 2 + kq * 16) ^ asw));
        short8 a1 = *(const short8*)(sb + (((16 + l16) * 2048 + kk * 2 + kq * 16) ^ asw));
        #pragma unroll
        for (int c = 0; c < 8; ++c){
          short8 bf = *(const short8*)(wcol[c] + kk);
          acc[0][c] = MFMA(a0, bf, acc[0][c], 0, 0, 0);
          acc[1][c] = MFMA(a1, bf, acc[1][c], 0, 0, 0);
        }
      }

      // contiguous 64KB slab, write-through to MALL
      unsigned short* gout = G2 + (((size_t)tt * 3 + g) * 2 + rhh) * 32768;
      #pragma unroll
      for (int c = 0; c < 8; ++c){
        int n = n0 + c * 16 + l16;
        #pragma unroll
        for (int r = 0; r < 2; ++r){
          unsigned lo = (unsigned)f2b(acc[r][c][0] + bias[c]) | ((unsigned)f2b(acc[r][c][1] + bias[c]) << 16);
          unsigned hi = (unsigned)f2b(acc[r][c][2] + bias[c]) | ((unsigned)f2b(acc[r][c][3] + bias[c]) << 16);
          pub8(&gout[(size_t)n * 32 + r * 16 + kq * 4],
               (unsigned long long)lo | ((unsigned long long)hi << 32));
        }
      }
      asm volatile("s_waitcnt vmcnt(0)" ::: "memory");   // per-thread drain
      __syncthreads();                                   // all 512 threads drained; smem reusable
      if (tid == 0)
        __hip_atomic_fetch_add(gready + tt * 32, 1, __ATOMIC_RELAXED, __HIP_MEMORY_SCOPE_AGENT);
    }
    return;
  }

  // ================= scan WG (r16/r17 structure) =================
  unsigned short* stage  = (unsigned short*)smem;            // 32 KiB
  float*          zlds   = (float*)(smem + 32768);           // 16*33 fp32
  float*          hlds   = (float*)(smem + 34880);           // 16*33 fp32
  unsigned short* ostage = (unsigned short*)(smem + 36992);  // 1 KiB

  const int rg  = bid & 3;
  const int cs  = bid >> 2;
  const int w    = tid >> 6;
  const int lane = tid & 63;
  const int l16  = lane & 15;
  const int kq   = lane >> 4;

  const int myct = (w < 4) ? (w & 1) : ((w < 6) ? (w - 4) : 0);
  const int col  = cs * 32 + myct * 16 + l16;
  const int gA   = (w >> 1) & 1;
  const int erow0 = kq * 4;
  const int ecol  = myct * 16 + l16;

  short8 wreg[32];
  if (w < 6){
    const int slot = (w < 2) ? 1 : (w < 4) ? 3 : 5;
    const unsigned short* p = wt + (size_t)slot * HID * HID + (size_t)col * HID + kq * 8;
    #pragma unroll
    for (int i = 0; i < 32; ++i) wreg[i] = *(const short8*)(p + i * 32);
  }

  int* fgrp   = flags + rg * 32 * 32;
  int* myflag = fgrp + cs * 32;

  for (int i = tid; i < 16 * 33; i += 512) hlds[i] = 0.f;
  __syncthreads();

  const int asw = (l16 & 7) << 4;
  const int abase = l16 * 2048 + kq * 16;
  const int pidx = tid - 448;
  const int prow = pidx >> 2, pc8 = (pidx & 3) * 8;

  const size_t g2rh = (size_t)(rg >> 1) * 32768;
  const int    g2r  = (rg & 1) * 16 + erow0;

  for (int t = 0; t < T_STEPS; ++t){
    unsigned short* hb_w = hb + (size_t)(t & (NSLOT - 1)) * SLOT_SH + rg * 16384;
    unsigned short* rh_w = rh + (size_t)(t & (NSLOT - 1)) * SLOT_SH + rg * 16384;
    const unsigned short* hb_r = hb + (size_t)((t - 1) & (NSLOT - 1)) * SLOT_SH + rg * 16384;

    // gate availability of this step's G2 tile (passes instantly in steady state)
    unsigned long long gx = 0;
    if (w < 6){
      const int* gp = gready + t * 32;
      int v = (lane == 0) ? __hip_atomic_load(gp, __ATOMIC_RELAXED, __HIP_MEMORY_SCOPE_AGENT) : 6;
      while (!__all(v >= 6)){
        __builtin_amdgcn_s_sleep(2);
        v = (lane == 0) ? __hip_atomic_load(gp, __ATOMIC_RELAXED, __HIP_MEMORY_SCOPE_AGENT) : 6;
      }
      const int gate = (w < 4) ? gA : 2;
      gx = __hip_atomic_load((const unsigned long long*)
             (G2 + ((size_t)t * 3 + gate) * 65536 + g2rh + (size_t)col * 32 + g2r),
             __ATOMIC_RELAXED, __HIP_MEMORY_SCOPE_AGENT);
    }

    // ---- phase A: Z / R gates (waves 0-3, full K) ----
    if (t){
      if (w == 0) waitflags32(fgrp, 2 * t);
      __syncthreads();
      stage_in(hb_r, stage, tid);
      __syncthreads();
    }
    if (w < 4){
      f32x4 a0 = {0.f,0.f,0.f,0.f}, a1 = {0.f,0.f,0.f,0.f};
      if (t){
        const char* sb = (const char*)stage;
        #pragma unroll
        for (int i = 0; i < 32; i += 2){
          short8 f0 = *(const short8*)(sb + ((abase + i * 64) ^ asw));
          short8 f1 = *(const short8*)(sb + ((abase + i * 64 + 64) ^ asw));
          a0 = MFMA(f0, wreg[i],     a0, 0, 0, 0);
          a1 = MFMA(f1, wreg[i + 1], a1, 0, 0, 0);
        }
      }
      #pragma unroll
      for (int j = 0; j < 4; ++j){
        float g = sigm(a0[j] + a1[j] + b2f((unsigned short)(gx >> (16 * j))));
        if (w < 2) zlds[(erow0 + j) * 33 + ecol] = g;
        else       ostage[(erow0 + j) * 32 + ecol] =
                     f2b(g * hlds[(erow0 + j) * 33 + ecol]);
      }
    }
    __syncthreads();

    // ---- exchange R*H: wave 7 publishes+flags while wave 0 polls ----
    if (t){
      if (tid >= 448) pub16(rh_w + prow * 1024 + cs * 32 + pc8, &ostage[prow * 32 + pc8]);
      if (tid == 448){
        asm volatile("s_waitcnt vmcnt(0)" ::: "memory");
        __hip_atomic_store(myflag, 2 * t + 1, __ATOMIC_RELAXED, __HIP_MEMORY_SCOPE_AGENT);
      }
      if (w == 0) waitflags32(fgrp, 2 * t + 1);
      __syncthreads();
      stage_in(rh_w, stage, tid);
      __syncthreads();
    }

    // ---- phase B: H_tilde + combine (waves 4-5, full K) ----
    float hn[4];
    if (w == 4 || w == 5){
      f32x4 a0 = {0.f,0.f,0.f,0.f}, a1 = {0.f,0.f,0.f,0.f};
      if (t){
        const char* sb = (const char*)stage;
        #pragma unroll
        for (int i = 0; i < 32; i += 2){
          short8 f0 = *(const short8*)(sb + ((abase + i * 64) ^ asw));
          short8 f1 = *(const short8*)(sb + ((abase + i * 64 + 64) ^ asw));
          a0 = MFMA(f0, wreg[i],     a0, 0, 0, 0);
          a1 = MFMA(f1, wreg[i + 1], a1, 0, 0, 0);
        }
      }
      #pragma unroll
      for (int j = 0; j < 4; ++j){
        int i33 = (erow0 + j) * 33 + ecol;
        float ht = tanh_fast(a0[j] + a1[j] + b2f((unsigned short)(gx >> (16 * j))));
        float z  = zlds[i33], hp = hlds[i33];
        hn[j] = z * hp + (1.0f - z) * ht;
        hlds[i33] = hn[j];
        ostage[(erow0 + j) * 32 + ecol] = f2b(hn[j]);
      }
    }
    __syncthreads();
    if (t < T_STEPS - 1){
      if (tid >= 448) pub16(hb_w + prow * 1024 + cs * 32 + pc8, &ostage[prow * 32 + pc8]);
      if (tid == 448){
        asm volatile("s_waitcnt vmcnt(0)" ::: "memory");
        __hip_atomic_store(myflag, 2 * t + 2, __ATOMIC_RELAXED, __HIP_MEMORY_SCOPE_AGENT);
      }
    }
    if (w == 4 || w == 5){
      #pragma unroll
      for (int j = 0; j < 4; ++j){
        __builtin_nontemporal_store(hn[j],
            &out[((size_t)t * BATCH + rg * 16 + erow0 + j) * HID + col]);
        if (t == T_STEPS - 1)
          __builtin_nontemporal_store(hn[j],
              &out[(size_t)T_STEPS * BATCH * HID + (size_t)(rg * 16 + erow0 + j) * HID + col]);
      }
    }
  }
}

extern "C" void kernel_launch(void* const* d_in, const int* in_sizes, int n_in,
                              void* d_out, int out_size, void* d_ws, size_t ws_size,
                              hipStream_t stream){
  const float* inputs = (const float*)d_in[0];
  const float* W_xz = (const float*)d_in[1];
  const float* W_hz = (const float*)d_in[2];
  const float* b_z  = (const float*)d_in[3];
  const float* W_xr = (const float*)d_in[4];
  const float* W_hr = (const float*)d_in[5];
  const float* b_r  = (const float*)d_in[6];
  const float* W_xh = (const float*)d_in[7];
  const float* W_hh = (const float*)d_in[8];
  const float* b_h  = (const float*)d_in[9];
  float* out = (float*)d_out;

  char* ws = (char*)d_ws;
  int*            flags  = (int*)ws;                                 // 16 KiB (128B-strided)
  int*            gready = (int*)(ws + 16384);                       // 64 KiB (128B-strided)
  unsigned short* hb     = (unsigned short*)(ws + 81920);            // 4 MiB (32 slots)
  unsigned short* rh     = (unsigned short*)(ws + 81920 + 4194304);  // 4 MiB
  unsigned short* wt     = (unsigned short*)(ws + 81920 + 8388608);  // 12 MiB
  unsigned short* G2     = (unsigned short*)(ws + 81920 + 8388608 + 12582912); // 192 MiB
  // total ws needed: ~213 MB

  gru_init_k<<<64, 256, 0, stream>>>(flags, gready);
  gru_prepw_k<<<dim3(32, 32, 6), dim3(32, 8), 0, stream>>>(W_xz, W_hz, W_xr, W_hr, W_xh, W_hh, wt);
  gru_main_k<<<NBLK, 512, 0, stream>>>(inputs, wt, b_z, b_r, b_h, G2, out, hb, rh, flags, gready);
}